// Round 4
// baseline (1155.093 us; speedup 1.0000x reference)
//
#include <hip/hip_runtime.h>

typedef __attribute__((ext_vector_type(8))) __bf16 bf16x8;
typedef __attribute__((ext_vector_type(4))) __bf16 bf16x4;
typedef __attribute__((ext_vector_type(4))) float floatx4;

#define B_DIM 2
#define S_DIM 2048
#define NH    32
#define NKV   8
#define HD    128
#define HID   4096

// ---------------------------------------------------------------- helpers
__device__ __forceinline__ void gload_lds16(const void* gsrc, void* ldst) {
  __builtin_amdgcn_global_load_lds(
      (__attribute__((address_space(1))) unsigned int*)(void*)gsrc,
      (__attribute__((address_space(3))) unsigned int*)ldst, 16, 0, 0);
}

// ---------------------------------------------------------------- fp32 -> bf16
__global__ void f2bf_kernel(const float* __restrict__ in, __bf16* __restrict__ out, int n) {
  int i = (blockIdx.x * 256 + threadIdx.x) * 4;
  if (i >= n) return;
  float4 v = *(const float4*)(in + i);
  bf16x4 o;
  o.x = (__bf16)v.x; o.y = (__bf16)v.y; o.z = (__bf16)v.z; o.w = (__bf16)v.w;
  *(bf16x4*)(out + i) = o;
}

// ---------------------------------------------------------------- GEMM C = A * B^T
// A [M][K] bf16 row-major, Bw [N][K] bf16 row-major.
// 128x128 tile, BK=32, double-buffered LDS + counted vmcnt prefetch pipeline.
// LDS unit XOR-swizzle (u ^= row&3) applied on BOTH the pre-swizzled global
// source (global_load_lds writes linearly) and the fragment read side.
// MODE 0: store bf16 permuted to Q layout [B,32,S,D]
// MODE 3: store fp32 plain row-major [M][N]
// MODE 4: merged K+V projection: col<1024 -> K layout [B,8,S,D];
//         col>=1024 -> Vt layout [B,8,D,S] at +4194304 bf16 elements.
__device__ __forceinline__ void gemm_stage(const __bf16* __restrict__ Ag,
                                           const __bf16* __restrict__ Bg,
                                           char* As, char* Bs, int K, int k0, int tid) {
#pragma unroll
  for (int i = 0; i < 2; i++) {
    int slot = i * 256 + tid;                  // 128 rows x 4 units (16 B)
    int row = slot >> 2;
    int u = (slot & 3) ^ (row & 3);            // inverse-swizzled source unit
    gload_lds16(Ag + (size_t)row * K + k0 + u * 8, As + slot * 16);
  }
#pragma unroll
  for (int i = 0; i < 2; i++) {
    int slot = i * 256 + tid;
    int row = slot >> 2;
    int u = (slot & 3) ^ (row & 3);
    gload_lds16(Bg + (size_t)row * K + k0 + u * 8, Bs + slot * 16);
  }
}

template <int MODE>
__global__ __launch_bounds__(256)
void gemm_bt(const __bf16* __restrict__ A, const __bf16* __restrict__ Bw,
             void* __restrict__ Cout, int M, int N, int K) {
  __shared__ uint4 smem4[2048];            // 32 KB: 2 x (As 8K + Bs 8K)
  char* smem = (char*)smem4;
  const int tid = threadIdx.x;
  const int lane = tid & 63, wave = tid >> 6;
  const int quad = lane >> 4, l16 = lane & 15;
  const int bm0 = blockIdx.y * 128, bn0 = blockIdx.x * 128;
  const __bf16* Ag = A + (size_t)bm0 * K;
  const __bf16* Bg = Bw + (size_t)bn0 * K;
  const int wm = (wave >> 1) * 64, wn = (wave & 1) * 64;

  floatx4 acc[4][4] = {};

  // prologue: stage K-tile 0 into buffer 0
  gemm_stage(Ag, Bg, smem, smem + 8192, K, 0, tid);

  const int nkt = K >> 5;
  for (int kt = 0; kt < nkt; kt++) {
    char* As = smem + (kt & 1) * 16384;
    char* Bs = As + 8192;

    if (kt + 1 < nkt) {
      char* An = smem + ((kt + 1) & 1) * 16384;
      gemm_stage(Ag, Bg, An, An + 8192, K, (kt + 1) << 5, tid);
      asm volatile("s_waitcnt vmcnt(4)" ::: "memory");   // current tile landed
    } else {
      asm volatile("s_waitcnt vmcnt(0)" ::: "memory");
    }
    __builtin_amdgcn_s_barrier();
    asm volatile("" ::: "memory");

    bf16x8 af[4], bfr[4];
#pragma unroll
    for (int i = 0; i < 4; i++) {
      int row = wm + i * 16 + l16;
      af[i] = *(const bf16x8*)(As + row * 64 + ((quad ^ (row & 3)) << 4));
    }
#pragma unroll
    for (int i = 0; i < 4; i++) {
      int row = wn + i * 16 + l16;
      bfr[i] = *(const bf16x8*)(Bs + row * 64 + ((quad ^ (row & 3)) << 4));
    }
#pragma unroll
    for (int mi = 0; mi < 4; mi++)
#pragma unroll
      for (int ni = 0; ni < 4; ni++)
        acc[mi][ni] = __builtin_amdgcn_mfma_f32_16x16x32_bf16(af[mi], bfr[ni], acc[mi][ni], 0, 0, 0);

    asm volatile("s_waitcnt lgkmcnt(0)" ::: "memory");   // frag reads complete
    __builtin_amdgcn_s_barrier();                        // buffer free for prefetch
    asm volatile("" ::: "memory");
  }

#pragma unroll
  for (int mi = 0; mi < 4; mi++)
#pragma unroll
    for (int ni = 0; ni < 4; ni++)
#pragma unroll
      for (int r = 0; r < 4; r++) {
        int row = bm0 + wm + mi * 16 + quad * 4 + r;   // m index (= b*2048+s)
        int col = bn0 + wn + ni * 16 + l16;            // n index
        float v = acc[mi][ni][r];
        if (MODE == 3) {
          ((float*)Cout)[(size_t)row * N + col] = v;
        } else if (MODE == 0) {
          int b = row >> 11, s = row & 2047;
          int h = col >> 7, d = col & 127;
          size_t idx = ((size_t)(b * NH + h) * S_DIM + s) * HD + d;
          ((__bf16*)Cout)[idx] = (__bf16)v;
        } else {  // MODE 4: merged K + Vt
          int b = row >> 11, s = row & 2047;
          size_t idx;
          if (col < 1024) {
            int h = col >> 7, d = col & 127;
            idx = ((size_t)(b * NKV + h) * S_DIM + s) * HD + d;              // K
          } else {
            int c = col - 1024;
            int h = c >> 7, d = c & 127;
            idx = 4194304 + ((size_t)(b * NKV + h) * HD + d) * S_DIM + s;    // Vt
          }
          ((__bf16*)Cout)[idx] = (__bf16)v;
        }
      }
}

// ---------------------------------------------------------------- RoPE (in place)
// x layout [B, nh, S, D]; pairs (j, j+64) rotated. lognh = log2(nh).
__global__ void rope_kernel(__bf16* __restrict__ x, const int* __restrict__ pos, int lognh) {
  int t = blockIdx.x * 256 + threadIdx.x;
  int j = t & 63;
  int s = (t >> 6) & (S_DIM - 1);
  int bh = t >> 17;
  int b = bh >> lognh;
  float p = (float)pos[b * S_DIM + s];
  float invf = exp2f((float)j * (-13.2877123795494f / 64.0f));
  float ang = p * invf;
  float sn, cs;
  sincosf(ang, &sn, &cs);
  size_t base = ((size_t)bh * S_DIM + s) * HD;
  float x1 = (float)x[base + j];
  float x2 = (float)x[base + j + 64];
  x[base + j]      = (__bf16)(x1 * cs - x2 * sn);
  x[base + j + 64] = (__bf16)(x2 * cs + x1 * sn);
}

// ---------------------------------------------------------------- flash attention
// Q [B,32,S,D], K [B,8,S,D], Vt [B,8,D,S] bf16 -> O [B,S,32*128] bf16.
// Block: 512 thr (8 waves), Q-tile 128 (16 q-rows/wave), K-tile 64, causal.
// Complementary Q-tile pairs (qt, 15-qt): every block does exactly 34 K-tiles,
// grid = 512 = 2 blocks/CU fully resident.
// Q in registers; K/V double-buffered in LDS via global_load_lds + counted vmcnt.
// Softmax denominator computed in the MATRIX pipe: oacc[8] accumulates P*ones.
// Defer-max (THR=8) skips rescale when tile max growth is small.
__device__ __forceinline__ void stage_kv(const __bf16* __restrict__ Kg,
                                         const __bf16* __restrict__ Vg,
                                         char* Kb, char* Vb, int k0, int tid) {
#pragma unroll
  for (int i = 0; i < 2; i++) {
    int slot = i * 512 + tid;                       // 64 rows x 16 units
    int row = slot >> 4;
    int u = (slot & 15) ^ (row & 15);               // inverse-swizzled source
    gload_lds16(Kg + (size_t)(k0 + row) * HD + u * 8, Kb + slot * 16);
  }
#pragma unroll
  for (int i = 0; i < 2; i++) {
    int slot = i * 512 + tid;                       // 128 rows x 8 units
    int row = slot >> 3;
    int u = (slot & 7) ^ (row & 7);
    gload_lds16(Vg + (size_t)row * S_DIM + k0 + u * 8, Vb + slot * 16);
  }
}

__global__ __launch_bounds__(512, 4)
void attn_kernel(const __bf16* __restrict__ Q, const __bf16* __restrict__ K,
                 const __bf16* __restrict__ Vt, __bf16* __restrict__ O) {
  __shared__ uint4 smem4[5120];            // 81920 B
  char* smem = (char*)smem4;
  char* Ps = smem + 65536;                 // 128 rows x 128 B
  const int tid = threadIdx.x;
  const int lane = tid & 63, wave = tid >> 6;
  const int quad = lane >> 4, l16 = lane & 15;
  const int h = blockIdx.y, b = blockIdx.z;
  const int kvh = h >> 2;
  const __bf16* Kg = K + (size_t)(b * NKV + kvh) * S_DIM * HD;
  const __bf16* Vg = Vt + (size_t)(b * NKV + kvh) * HD * S_DIM;
  const float scale = 0.08838834764831845f;   // 1/sqrt(128)

  bf16x8 ones;
#pragma unroll
  for (int j = 0; j < 8; j++) ones[j] = (__bf16)1.0f;

  for (int pass = 0; pass < 2; ++pass) {
    const int qt = pass ? (15 - (int)blockIdx.x) : (int)blockIdx.x;
    const int q0 = qt * 128;
    const __bf16* Qg = Q + ((size_t)(b * NH + h) * S_DIM + q0) * HD;
    const int nkt = qt * 2 + 2;

    // Q fragments in registers (wave owns 16 q-rows)
    bf16x8 qf[4];
#pragma unroll
    for (int ks = 0; ks < 4; ks++)
      qf[ks] = *(const bf16x8*)(Qg + (wave * 16 + l16) * HD + (ks * 4 + quad) * 8);

    floatx4 oacc[9] = {};                       // [8] = row-sum (denominator)
    float mrow[4] = {-1e30f, -1e30f, -1e30f, -1e30f};

    // prologue: stage tile 0 into buffer 0
    stage_kv(Kg, Vg, smem, smem + 32768, 0, tid);

    for (int kt = 0; kt < nkt; kt++) {
      char* Kc = smem + (kt & 1) * 16384;
      char* Vc = smem + 32768 + (kt & 1) * 16384;
      const int k0 = kt * 64;

      if (kt + 1 < nkt) {
        stage_kv(Kg, Vg, smem + ((kt + 1) & 1) * 16384,
                 smem + 32768 + ((kt + 1) & 1) * 16384, k0 + 64, tid);
        asm volatile("s_waitcnt vmcnt(4)" ::: "memory");
      } else {
        asm volatile("s_waitcnt vmcnt(0)" ::: "memory");
      }
      __builtin_amdgcn_s_barrier();            // tile kt data visible to all waves
      asm volatile("" ::: "memory");

      // ---- S = Q K^T
      floatx4 sacc[4] = {};
      __builtin_amdgcn_s_setprio(1);
#pragma unroll
      for (int ks = 0; ks < 4; ks++) {
        bf16x8 bk[4];
#pragma unroll
        for (int n = 0; n < 4; n++) {
          int row = n * 16 + l16;
          bk[n] = *(const bf16x8*)(Kc + row * 256 + (((ks * 4 + quad) ^ (row & 15)) << 4));
        }
#pragma unroll
        for (int n = 0; n < 4; n++)
          sacc[n] = __builtin_amdgcn_mfma_f32_16x16x32_bf16(qf[ks], bk[n], sacc[n], 0, 0, 0);
      }
      __builtin_amdgcn_s_setprio(0);

      // ---- online softmax (rows wave-private; max-reduce over 16 lanes)
      const bool maskt = (kt >= nkt - 2);      // diagonal-crossing tiles
      float pm[4][4];
      float rmax[4] = {-3e30f, -3e30f, -3e30f, -3e30f};
#pragma unroll
      for (int n = 0; n < 4; n++)
#pragma unroll
        for (int r = 0; r < 4; r++) {
          float sv = sacc[n][r] * scale;
          if (maskt) {
            int qrow = q0 + wave * 16 + quad * 4 + r;
            int kcol = k0 + n * 16 + l16;
            if (kcol > qrow) sv = -1e30f;
          }
          pm[n][r] = sv;
          rmax[r] = fmaxf(rmax[r], sv);
        }
      float vr[4];
#pragma unroll
      for (int r = 0; r < 4; r++) {
        float v = rmax[r];
        v = fmaxf(v, __shfl_xor(v, 1));
        v = fmaxf(v, __shfl_xor(v, 2));
        v = fmaxf(v, __shfl_xor(v, 4));
        v = fmaxf(v, __shfl_xor(v, 8));
        vr[r] = v;
      }
      bool small = (vr[0] <= mrow[0] + 8.f) && (vr[1] <= mrow[1] + 8.f) &&
                   (vr[2] <= mrow[2] + 8.f) && (vr[3] <= mrow[3] + 8.f);
      if (__all(small ? 1 : 0)) {
        // defer-max: keep old reference max; P bounded by e^8
#pragma unroll
        for (int r = 0; r < 4; r++)
#pragma unroll
          for (int n = 0; n < 4; n++) pm[n][r] = __expf(pm[n][r] - mrow[r]);
      } else {
#pragma unroll
        for (int r = 0; r < 4; r++) {
          float nm = fmaxf(mrow[r], vr[r]);
          float al = __expf(mrow[r] - nm);
          mrow[r] = nm;
#pragma unroll
          for (int n = 0; n < 4; n++) pm[n][r] = __expf(pm[n][r] - nm);
#pragma unroll
          for (int n = 0; n < 9; n++) oacc[n][r] *= al;
        }
      }
      // write P (bf16) to LDS — wave-private rows, no barrier needed
#pragma unroll
      for (int n = 0; n < 4; n++)
#pragma unroll
        for (int r = 0; r < 4; r++) {
          int row = wave * 16 + quad * 4 + r;
          int col = n * 16 + l16;
          *(__bf16*)(Ps + row * 128 + (((col >> 3) ^ (row & 7)) << 4) + (col & 7) * 2) =
              (__bf16)pm[n][r];
        }
      asm volatile("s_waitcnt lgkmcnt(0)" ::: "memory");   // P writes landed

      // ---- O += P V ; denominator += P * ones (matrix pipe)
      __builtin_amdgcn_s_setprio(1);
#pragma unroll
      for (int ks = 0; ks < 2; ks++) {
        int prow = wave * 16 + l16;
        bf16x8 ap = *(const bf16x8*)(Ps + prow * 128 + (((ks * 4 + quad) ^ (prow & 7)) << 4));
#pragma unroll
        for (int n = 0; n < 8; n++) {
          int vrow = n * 16 + l16;
          bf16x8 bv = *(const bf16x8*)(Vc + vrow * 128 + (((ks * 4 + quad) ^ (vrow & 7)) << 4));
          oacc[n] = __builtin_amdgcn_mfma_f32_16x16x32_bf16(ap, bv, oacc[n], 0, 0, 0);
        }
        oacc[8] = __builtin_amdgcn_mfma_f32_16x16x32_bf16(ap, ones, oacc[8], 0, 0, 0);
      }
      __builtin_amdgcn_s_setprio(0);

      asm volatile("" ::: "memory");
      __builtin_amdgcn_s_barrier();            // buffers free for next prefetch
      asm volatile("" ::: "memory");
    }

    // epilogue: O /= l, store to [B,S,H*D]
#pragma unroll
    for (int n = 0; n < 8; n++)
#pragma unroll
      for (int r = 0; r < 4; r++) {
        int row = wave * 16 + quad * 4 + r;
        int col = n * 16 + l16;
        float v = oacc[n][r] / oacc[8][r];
        O[(size_t)(b * S_DIM + q0 + row) * HID + h * HD + col] = (__bf16)v;
      }
  }
}

// ---------------------------------------------------------------- launch
extern "C" void kernel_launch(void* const* d_in, const int* in_sizes, int n_in,
                              void* d_out, int out_size, void* d_ws, size_t ws_size,
                              hipStream_t stream) {
  const float* hs = (const float*)d_in[0];
  const float* wq = (const float*)d_in[1];
  const float* wk = (const float*)d_in[2];
  const float* wv = (const float*)d_in[3];
  const float* wo = (const float*)d_in[4];
  // d_in[5] = attention_mask (pure causal; implemented directly)
  const int* pos = (const int*)d_in[6];

  char* ws = (char*)d_ws;
  __bf16* Xb  = (__bf16*)(ws);                 // 33.55 MB  [4096][4096]
  __bf16* Wqb = (__bf16*)(ws + 33554432);      // 33.55 MB
  __bf16* Wkb = (__bf16*)(ws + 67108864);      //  8.39 MB (contig with Wvb)
  __bf16* Wvb = (__bf16*)(ws + 75497472);      //  8.39 MB
  __bf16* Wob = (__bf16*)(ws + 83886080);      // 33.55 MB
  __bf16* Qb  = (__bf16*)(ws + 117440512);     // 33.55 MB  [B,32,S,D]
  __bf16* Kb  = (__bf16*)(ws + 150994944);     //  8.39 MB  [B,8,S,D] (contig with Vtb)
  __bf16* Vtb = (__bf16*)(ws + 159383552);     //  8.39 MB  [B,8,D,S]
  __bf16* Ab  = (__bf16*)(ws + 167772160);     // 33.55 MB  attn out [4096][4096]
  if (ws_size < 201326592u) return;

  const int M = B_DIM * S_DIM;  // 4096

  f2bf_kernel<<<16384, 256, 0, stream>>>(hs, Xb, 16777216);
  f2bf_kernel<<<16384, 256, 0, stream>>>(wq, Wqb, 16777216);
  f2bf_kernel<<<4096, 256, 0, stream>>>(wk, Wkb, 4194304);
  f2bf_kernel<<<4096, 256, 0, stream>>>(wv, Wvb, 4194304);
  f2bf_kernel<<<16384, 256, 0, stream>>>(wo, Wob, 16777216);

  gemm_bt<0><<<dim3(32, 32), 256, 0, stream>>>(Xb, Wqb, Qb, M, 4096, 4096);
  // merged K+V projection: Wkb|Wvb contiguous [2048][4096], Kb|Vtb contiguous out
  gemm_bt<4><<<dim3(16, 32), 256, 0, stream>>>(Xb, Wkb, Kb, M, 2048, 4096);

  rope_kernel<<<32768, 256, 0, stream>>>(Qb, pos, 5);   // B*32*2048*64 / 256
  rope_kernel<<<8192, 256, 0, stream>>>(Kb, pos, 3);    // B*8*2048*64 / 256

  attn_kernel<<<dim3(8, 32, 2), 512, 0, stream>>>(Qb, Kb, Vtb, Ab);

  gemm_bt<3><<<dim3(32, 32), 256, 0, stream>>>(Ab, Wob, d_out, M, 4096, 4096);
}

// Round 5
// 847.209 us; speedup vs baseline: 1.3634x; 1.3634x over previous
//
#include <hip/hip_runtime.h>

typedef __attribute__((ext_vector_type(8))) __bf16 bf16x8;
typedef __attribute__((ext_vector_type(4))) __bf16 bf16x4;
typedef __attribute__((ext_vector_type(4))) float floatx4;

#define B_DIM 2
#define S_DIM 2048
#define NH    32
#define NKV   8
#define HD    128
#define HID   4096

// ---------------------------------------------------------------- helpers
__device__ __forceinline__ void gload_lds16(const void* gsrc, void* ldst) {
  __builtin_amdgcn_global_load_lds(
      (__attribute__((address_space(1))) unsigned int*)(void*)gsrc,
      (__attribute__((address_space(3))) unsigned int*)ldst, 16, 0, 0);
}

// ---------------------------------------------------------------- fp32 -> bf16
__global__ void f2bf_kernel(const float* __restrict__ in, __bf16* __restrict__ out, int n) {
  int i = (blockIdx.x * 256 + threadIdx.x) * 4;
  if (i >= n) return;
  float4 v = *(const float4*)(in + i);
  bf16x4 o;
  o.x = (__bf16)v.x; o.y = (__bf16)v.y; o.z = (__bf16)v.z; o.w = (__bf16)v.w;
  *(bf16x4*)(out + i) = o;
}

// ---------------------------------------------------------------- GEMM C = A * B^T
// A [M][K] bf16 row-major, Bw [N][K] bf16 row-major.
// 128x128 tile, BK=32, double-buffered LDS + counted vmcnt prefetch pipeline.
// LDS unit XOR-swizzle (u ^= row&3) applied on BOTH the pre-swizzled global
// source (global_load_lds writes linearly) and the fragment read side.
// MODE 0: store bf16 permuted to Q layout [B,32,S,D]
// MODE 3: store fp32 plain row-major [M][N]
// MODE 4: merged K+V projection: col<1024 -> K layout [B,8,S,D];
//         col>=1024 -> Vt layout [B,8,D,S] at +4194304 bf16 elements.
__device__ __forceinline__ void gemm_stage(const __bf16* __restrict__ Ag,
                                           const __bf16* __restrict__ Bg,
                                           char* As, char* Bs, int K, int k0, int tid) {
#pragma unroll
  for (int i = 0; i < 2; i++) {
    int slot = i * 256 + tid;                  // 128 rows x 4 units (16 B)
    int row = slot >> 2;
    int u = (slot & 3) ^ (row & 3);            // inverse-swizzled source unit
    gload_lds16(Ag + (size_t)row * K + k0 + u * 8, As + slot * 16);
  }
#pragma unroll
  for (int i = 0; i < 2; i++) {
    int slot = i * 256 + tid;
    int row = slot >> 2;
    int u = (slot & 3) ^ (row & 3);
    gload_lds16(Bg + (size_t)row * K + k0 + u * 8, Bs + slot * 16);
  }
}

template <int MODE>
__global__ __launch_bounds__(256)
void gemm_bt(const __bf16* __restrict__ A, const __bf16* __restrict__ Bw,
             void* __restrict__ Cout, int M, int N, int K) {
  __shared__ uint4 smem4[2048];            // 32 KB: 2 x (As 8K + Bs 8K)
  char* smem = (char*)smem4;
  const int tid = threadIdx.x;
  const int lane = tid & 63, wave = tid >> 6;
  const int quad = lane >> 4, l16 = lane & 15;
  const int bm0 = blockIdx.y * 128, bn0 = blockIdx.x * 128;
  const __bf16* Ag = A + (size_t)bm0 * K;
  const __bf16* Bg = Bw + (size_t)bn0 * K;
  const int wm = (wave >> 1) * 64, wn = (wave & 1) * 64;

  floatx4 acc[4][4] = {};

  // prologue: stage K-tile 0 into buffer 0
  gemm_stage(Ag, Bg, smem, smem + 8192, K, 0, tid);

  const int nkt = K >> 5;
  for (int kt = 0; kt < nkt; kt++) {
    char* As = smem + (kt & 1) * 16384;
    char* Bs = As + 8192;

    if (kt + 1 < nkt) {
      char* An = smem + ((kt + 1) & 1) * 16384;
      gemm_stage(Ag, Bg, An, An + 8192, K, (kt + 1) << 5, tid);
      asm volatile("s_waitcnt vmcnt(4)" ::: "memory");   // current tile landed
    } else {
      asm volatile("s_waitcnt vmcnt(0)" ::: "memory");
    }
    __builtin_amdgcn_s_barrier();
    asm volatile("" ::: "memory");

    bf16x8 af[4], bfr[4];
#pragma unroll
    for (int i = 0; i < 4; i++) {
      int row = wm + i * 16 + l16;
      af[i] = *(const bf16x8*)(As + row * 64 + ((quad ^ (row & 3)) << 4));
    }
#pragma unroll
    for (int i = 0; i < 4; i++) {
      int row = wn + i * 16 + l16;
      bfr[i] = *(const bf16x8*)(Bs + row * 64 + ((quad ^ (row & 3)) << 4));
    }
#pragma unroll
    for (int mi = 0; mi < 4; mi++)
#pragma unroll
      for (int ni = 0; ni < 4; ni++)
        acc[mi][ni] = __builtin_amdgcn_mfma_f32_16x16x32_bf16(af[mi], bfr[ni], acc[mi][ni], 0, 0, 0);

    asm volatile("s_waitcnt lgkmcnt(0)" ::: "memory");   // frag reads complete
    __builtin_amdgcn_s_barrier();                        // buffer free for prefetch
    asm volatile("" ::: "memory");
  }

#pragma unroll
  for (int mi = 0; mi < 4; mi++)
#pragma unroll
    for (int ni = 0; ni < 4; ni++)
#pragma unroll
      for (int r = 0; r < 4; r++) {
        int row = bm0 + wm + mi * 16 + quad * 4 + r;   // m index (= b*2048+s)
        int col = bn0 + wn + ni * 16 + l16;            // n index
        float v = acc[mi][ni][r];
        if (MODE == 3) {
          ((float*)Cout)[(size_t)row * N + col] = v;
        } else if (MODE == 0) {
          int b = row >> 11, s = row & 2047;
          int h = col >> 7, d = col & 127;
          size_t idx = ((size_t)(b * NH + h) * S_DIM + s) * HD + d;
          ((__bf16*)Cout)[idx] = (__bf16)v;
        } else {  // MODE 4: merged K + Vt
          int b = row >> 11, s = row & 2047;
          size_t idx;
          if (col < 1024) {
            int h = col >> 7, d = col & 127;
            idx = ((size_t)(b * NKV + h) * S_DIM + s) * HD + d;              // K
          } else {
            int c = col - 1024;
            int h = c >> 7, d = c & 127;
            idx = 4194304 + ((size_t)(b * NKV + h) * HD + d) * S_DIM + s;    // Vt
          }
          ((__bf16*)Cout)[idx] = (__bf16)v;
        }
      }
}

// ---------------------------------------------------------------- RoPE (in place)
// x layout [B, nh, S, D]; pairs (j, j+64) rotated. lognh = log2(nh).
__global__ void rope_kernel(__bf16* __restrict__ x, const int* __restrict__ pos, int lognh) {
  int t = blockIdx.x * 256 + threadIdx.x;
  int j = t & 63;
  int s = (t >> 6) & (S_DIM - 1);
  int bh = t >> 17;
  int b = bh >> lognh;
  float p = (float)pos[b * S_DIM + s];
  float invf = exp2f((float)j * (-13.2877123795494f / 64.0f));
  float ang = p * invf;
  float sn, cs;
  sincosf(ang, &sn, &cs);
  size_t base = ((size_t)bh * S_DIM + s) * HD;
  float x1 = (float)x[base + j];
  float x2 = (float)x[base + j + 64];
  x[base + j]      = (__bf16)(x1 * cs - x2 * sn);
  x[base + j + 64] = (__bf16)(x2 * cs + x1 * sn);
}

// ---------------------------------------------------------------- flash attention
// Q [B,32,S,D], K [B,8,S,D], Vt [B,8,D,S] bf16 -> O [B,S,32*128] bf16.
// Block: 512 thr (8 waves), Q-tile 128 (16 q-rows/wave), K-tile 64, causal.
// Each block processes TWO complementary Q-tiles (qt, 15-qt) -> every block
// does exactly 34 K-tiles: perfect static balance, grid = 512 = 2 blocks/CU
// fully resident (no dispatch rounds).
// Q held in registers. K/V double-buffered in LDS, staged async via
// global_load_lds (linear LDS dest, pre-swizzled global source), counted vmcnt.
// LDS 80 KB: K dbuf 2x16K (XOR-15 swz) | V dbuf 2x16K (XOR-7) | Ps 16K (XOR-7)
// NOTE (R4 lesson): adding a 9th MFMA accumulator + defer-max branch spilled
// to scratch inside the K-loop (WRITE_SIZE 63->656 MB) — keep state lean.
__device__ __forceinline__ void stage_kv(const __bf16* __restrict__ Kg,
                                         const __bf16* __restrict__ Vg,
                                         char* Kb, char* Vb, int k0, int tid) {
#pragma unroll
  for (int i = 0; i < 2; i++) {
    int slot = i * 512 + tid;                       // 64 rows x 16 units
    int row = slot >> 4;
    int u = (slot & 15) ^ (row & 15);               // inverse-swizzled source
    gload_lds16(Kg + (size_t)(k0 + row) * HD + u * 8, Kb + slot * 16);
  }
#pragma unroll
  for (int i = 0; i < 2; i++) {
    int slot = i * 512 + tid;                       // 128 rows x 8 units
    int row = slot >> 3;
    int u = (slot & 7) ^ (row & 7);
    gload_lds16(Vg + (size_t)row * S_DIM + k0 + u * 8, Vb + slot * 16);
  }
}

__global__ __launch_bounds__(512, 4)
void attn_kernel(const __bf16* __restrict__ Q, const __bf16* __restrict__ K,
                 const __bf16* __restrict__ Vt, __bf16* __restrict__ O) {
  __shared__ uint4 smem4[5120];            // 81920 B
  char* smem = (char*)smem4;
  char* Ps = smem + 65536;                 // 128 rows x 128 B
  const int tid = threadIdx.x;
  const int lane = tid & 63, wave = tid >> 6;
  const int quad = lane >> 4, l16 = lane & 15;
  const int h = blockIdx.y, b = blockIdx.z;
  const int kvh = h >> 2;
  const __bf16* Kg = K + (size_t)(b * NKV + kvh) * S_DIM * HD;
  const __bf16* Vg = Vt + (size_t)(b * NKV + kvh) * HD * S_DIM;
  const float scale = 0.08838834764831845f;   // 1/sqrt(128)

  for (int pass = 0; pass < 2; ++pass) {
    const int qt = pass ? (15 - (int)blockIdx.x) : (int)blockIdx.x;
    const int q0 = qt * 128;
    const __bf16* Qg = Q + ((size_t)(b * NH + h) * S_DIM + q0) * HD;
    const int nkt = qt * 2 + 2;

    // Q fragments in registers (wave owns 16 q-rows)
    bf16x8 qf[4];
#pragma unroll
    for (int ks = 0; ks < 4; ks++)
      qf[ks] = *(const bf16x8*)(Qg + (wave * 16 + l16) * HD + (ks * 4 + quad) * 8);

    floatx4 oacc[8] = {};
    float mrow[4] = {-1e30f, -1e30f, -1e30f, -1e30f};
    float lrow[4] = {0.f, 0.f, 0.f, 0.f};

    // prologue: stage tile 0 into buffer 0
    stage_kv(Kg, Vg, smem, smem + 32768, 0, tid);

    for (int kt = 0; kt < nkt; kt++) {
      char* Kc = smem + (kt & 1) * 16384;
      char* Vc = smem + 32768 + (kt & 1) * 16384;
      const int k0 = kt * 64;

      if (kt + 1 < nkt) {
        // issue next tile's 4 DMA loads/thread into the other buffer, then
        // wait only for the current tile's 4 (counted vmcnt)
        stage_kv(Kg, Vg, smem + ((kt + 1) & 1) * 16384,
                 smem + 32768 + ((kt + 1) & 1) * 16384, k0 + 64, tid);
        asm volatile("s_waitcnt vmcnt(4)" ::: "memory");
      } else {
        asm volatile("s_waitcnt vmcnt(0)" ::: "memory");
      }
      __builtin_amdgcn_s_barrier();            // tile kt data visible to all waves
      asm volatile("" ::: "memory");

      // ---- S = Q K^T
      floatx4 sacc[4] = {};
#pragma unroll
      for (int ks = 0; ks < 4; ks++) {
        bf16x8 bk[4];
#pragma unroll
        for (int n = 0; n < 4; n++) {
          int row = n * 16 + l16;
          bk[n] = *(const bf16x8*)(Kc + row * 256 + (((ks * 4 + quad) ^ (row & 15)) << 4));
        }
#pragma unroll
        for (int n = 0; n < 4; n++)
          sacc[n] = __builtin_amdgcn_mfma_f32_16x16x32_bf16(qf[ks], bk[n], sacc[n], 0, 0, 0);
      }

      // ---- online softmax (rows wave-private)
      const bool maskt = (kt >= nkt - 2);      // diagonal-crossing tiles
      float pm[4][4];
      float rmax[4] = {-3e30f, -3e30f, -3e30f, -3e30f};
#pragma unroll
      for (int n = 0; n < 4; n++)
#pragma unroll
        for (int r = 0; r < 4; r++) {
          float sv = sacc[n][r] * scale;
          if (maskt) {
            int qrow = q0 + wave * 16 + quad * 4 + r;
            int kcol = k0 + n * 16 + l16;
            if (kcol > qrow) sv = -1e30f;
          }
          pm[n][r] = sv;
          rmax[r] = fmaxf(rmax[r], sv);
        }
#pragma unroll
      for (int r = 0; r < 4; r++) {
        float v = rmax[r];
        v = fmaxf(v, __shfl_xor(v, 1));
        v = fmaxf(v, __shfl_xor(v, 2));
        v = fmaxf(v, __shfl_xor(v, 4));
        v = fmaxf(v, __shfl_xor(v, 8));
        float nm = fmaxf(mrow[r], v);
        float al = __expf(mrow[r] - nm);
        mrow[r] = nm;
        float rs = 0.f;
#pragma unroll
        for (int n = 0; n < 4; n++) {
          float p = __expf(pm[n][r] - nm);
          pm[n][r] = p;
          rs += p;
        }
        rs += __shfl_xor(rs, 1);
        rs += __shfl_xor(rs, 2);
        rs += __shfl_xor(rs, 4);
        rs += __shfl_xor(rs, 8);
        lrow[r] = lrow[r] * al + rs;
#pragma unroll
        for (int n = 0; n < 8; n++) oacc[n][r] *= al;
      }
      // write P (bf16) to LDS — wave-private rows, no barrier needed
#pragma unroll
      for (int n = 0; n < 4; n++)
#pragma unroll
        for (int r = 0; r < 4; r++) {
          int row = wave * 16 + quad * 4 + r;
          int col = n * 16 + l16;
          *(__bf16*)(Ps + row * 128 + (((col >> 3) ^ (row & 7)) << 4) + (col & 7) * 2) =
              (__bf16)pm[n][r];
        }
      asm volatile("s_waitcnt lgkmcnt(0)" ::: "memory");   // P writes landed

      // ---- O += P V
#pragma unroll
      for (int ks = 0; ks < 2; ks++) {
        int prow = wave * 16 + l16;
        bf16x8 ap = *(const bf16x8*)(Ps + prow * 128 + (((ks * 4 + quad) ^ (prow & 7)) << 4));
#pragma unroll
        for (int n = 0; n < 8; n++) {
          int vrow = n * 16 + l16;
          bf16x8 bv = *(const bf16x8*)(Vc + vrow * 128 + (((ks * 4 + quad) ^ (vrow & 7)) << 4));
          oacc[n] = __builtin_amdgcn_mfma_f32_16x16x32_bf16(ap, bv, oacc[n], 0, 0, 0);
        }
      }

      asm volatile("" ::: "memory");
      __builtin_amdgcn_s_barrier();            // buffers free for next prefetch
      asm volatile("" ::: "memory");
    }

    // epilogue: O /= l, store to [B,S,H*D]
#pragma unroll
    for (int n = 0; n < 8; n++)
#pragma unroll
      for (int r = 0; r < 4; r++) {
        int row = wave * 16 + quad * 4 + r;
        int col = n * 16 + l16;
        float v = oacc[n][r] / lrow[r];
        O[(size_t)(b * S_DIM + q0 + row) * HID + h * HD + col] = (__bf16)v;
      }
  }
}

// ---------------------------------------------------------------- launch
extern "C" void kernel_launch(void* const* d_in, const int* in_sizes, int n_in,
                              void* d_out, int out_size, void* d_ws, size_t ws_size,
                              hipStream_t stream) {
  const float* hs = (const float*)d_in[0];
  const float* wq = (const float*)d_in[1];
  const float* wk = (const float*)d_in[2];
  const float* wv = (const float*)d_in[3];
  const float* wo = (const float*)d_in[4];
  // d_in[5] = attention_mask (pure causal; implemented directly)
  const int* pos = (const int*)d_in[6];

  char* ws = (char*)d_ws;
  __bf16* Xb  = (__bf16*)(ws);                 // 33.55 MB  [4096][4096]
  __bf16* Wqb = (__bf16*)(ws + 33554432);      // 33.55 MB
  __bf16* Wkb = (__bf16*)(ws + 67108864);      //  8.39 MB (contig with Wvb)
  __bf16* Wvb = (__bf16*)(ws + 75497472);      //  8.39 MB
  __bf16* Wob = (__bf16*)(ws + 83886080);      // 33.55 MB
  __bf16* Qb  = (__bf16*)(ws + 117440512);     // 33.55 MB  [B,32,S,D]
  __bf16* Kb  = (__bf16*)(ws + 150994944);     //  8.39 MB  [B,8,S,D] (contig with Vtb)
  __bf16* Vtb = (__bf16*)(ws + 159383552);     //  8.39 MB  [B,8,D,S]
  __bf16* Ab  = (__bf16*)(ws + 167772160);     // 33.55 MB  attn out [4096][4096]
  if (ws_size < 201326592u) return;

  const int M = B_DIM * S_DIM;  // 4096

  f2bf_kernel<<<16384, 256, 0, stream>>>(hs, Xb, 16777216);
  f2bf_kernel<<<16384, 256, 0, stream>>>(wq, Wqb, 16777216);
  f2bf_kernel<<<4096, 256, 0, stream>>>(wk, Wkb, 4194304);
  f2bf_kernel<<<4096, 256, 0, stream>>>(wv, Wvb, 4194304);
  f2bf_kernel<<<16384, 256, 0, stream>>>(wo, Wob, 16777216);

  gemm_bt<0><<<dim3(32, 32), 256, 0, stream>>>(Xb, Wqb, Qb, M, 4096, 4096);
  // merged K+V projection: Wkb|Wvb contiguous [2048][4096], Kb|Vtb contiguous out
  gemm_bt<4><<<dim3(16, 32), 256, 0, stream>>>(Xb, Wkb, Kb, M, 2048, 4096);

  rope_kernel<<<32768, 256, 0, stream>>>(Qb, pos, 5);   // B*32*2048*64 / 256
  rope_kernel<<<8192, 256, 0, stream>>>(Kb, pos, 3);    // B*8*2048*64 / 256

  attn_kernel<<<dim3(8, 32, 2), 512, 0, stream>>>(Qb, Kb, Vtb, Ab);

  gemm_bt<3><<<dim3(32, 32), 256, 0, stream>>>(Ab, Wob, d_out, M, 4096, 4096);
}

// Round 7
// 791.143 us; speedup vs baseline: 1.4600x; 1.0709x over previous
//
#include <hip/hip_runtime.h>

typedef __attribute__((ext_vector_type(8))) __bf16 bf16x8;
typedef __attribute__((ext_vector_type(4))) __bf16 bf16x4;
typedef __attribute__((ext_vector_type(4))) float floatx4;

#define B_DIM 2
#define S_DIM 2048
#define NH    32
#define NKV   8
#define HD    128
#define HID   4096

// ---------------------------------------------------------------- helpers
__device__ __forceinline__ void gload_lds16(const void* gsrc, void* ldst) {
  __builtin_amdgcn_global_load_lds(
      (__attribute__((address_space(1))) unsigned int*)(void*)gsrc,
      (__attribute__((address_space(3))) unsigned int*)ldst, 16, 0, 0);
}

// ---------------------------------------------------------------- fp32 -> bf16
__global__ void f2bf_kernel(const float* __restrict__ in, __bf16* __restrict__ out, int n) {
  int i = (blockIdx.x * 256 + threadIdx.x) * 4;
  if (i >= n) return;
  float4 v = *(const float4*)(in + i);
  bf16x4 o;
  o.x = (__bf16)v.x; o.y = (__bf16)v.y; o.z = (__bf16)v.z; o.w = (__bf16)v.w;
  *(bf16x4*)(out + i) = o;
}

// ---------------------------------------------------------------- GEMM C = A * B^T
// A [M][K] bf16 row-major, Bw [N][K] bf16 row-major.
// 128x128 tile, BK=32, double-buffered LDS + counted vmcnt prefetch pipeline.
// LDS unit XOR-swizzle (u ^= row&3) applied on BOTH the pre-swizzled global
// source (global_load_lds writes linearly) and the fragment read side.
// MODE 0: store bf16 permuted to Q layout [B,32,S,D]
// MODE 3: store fp32 plain row-major [M][N]
// MODE 4: merged K+V projection: col<1024 -> K layout [B,8,S,D];
//         col>=1024 -> Vt layout [B,8,D,S] at +4194304 bf16 elements.
__device__ __forceinline__ void gemm_stage(const __bf16* __restrict__ Ag,
                                           const __bf16* __restrict__ Bg,
                                           char* As, char* Bs, int K, int k0, int tid) {
#pragma unroll
  for (int i = 0; i < 2; i++) {
    int slot = i * 256 + tid;                  // 128 rows x 4 units (16 B)
    int row = slot >> 2;
    int u = (slot & 3) ^ (row & 3);            // inverse-swizzled source unit
    gload_lds16(Ag + (size_t)row * K + k0 + u * 8, As + slot * 16);
  }
#pragma unroll
  for (int i = 0; i < 2; i++) {
    int slot = i * 256 + tid;
    int row = slot >> 2;
    int u = (slot & 3) ^ (row & 3);
    gload_lds16(Bg + (size_t)row * K + k0 + u * 8, Bs + slot * 16);
  }
}

template <int MODE>
__global__ __launch_bounds__(256)
void gemm_bt(const __bf16* __restrict__ A, const __bf16* __restrict__ Bw,
             void* __restrict__ Cout, int M, int N, int K) {
  __shared__ uint4 smem4[2048];            // 32 KB: 2 x (As 8K + Bs 8K)
  char* smem = (char*)smem4;
  const int tid = threadIdx.x;
  const int lane = tid & 63, wave = tid >> 6;
  const int quad = lane >> 4, l16 = lane & 15;
  const int bm0 = blockIdx.y * 128, bn0 = blockIdx.x * 128;
  const __bf16* Ag = A + (size_t)bm0 * K;
  const __bf16* Bg = Bw + (size_t)bn0 * K;
  const int wm = (wave >> 1) * 64, wn = (wave & 1) * 64;

  floatx4 acc[4][4] = {};

  // prologue: stage K-tile 0 into buffer 0
  gemm_stage(Ag, Bg, smem, smem + 8192, K, 0, tid);

  const int nkt = K >> 5;
  for (int kt = 0; kt < nkt; kt++) {
    char* As = smem + (kt & 1) * 16384;
    char* Bs = As + 8192;

    if (kt + 1 < nkt) {
      char* An = smem + ((kt + 1) & 1) * 16384;
      gemm_stage(Ag, Bg, An, An + 8192, K, (kt + 1) << 5, tid);
      asm volatile("s_waitcnt vmcnt(4)" ::: "memory");   // current tile landed
    } else {
      asm volatile("s_waitcnt vmcnt(0)" ::: "memory");
    }
    __builtin_amdgcn_s_barrier();
    asm volatile("" ::: "memory");

    bf16x8 af[4], bfr[4];
#pragma unroll
    for (int i = 0; i < 4; i++) {
      int row = wm + i * 16 + l16;
      af[i] = *(const bf16x8*)(As + row * 64 + ((quad ^ (row & 3)) << 4));
    }
#pragma unroll
    for (int i = 0; i < 4; i++) {
      int row = wn + i * 16 + l16;
      bfr[i] = *(const bf16x8*)(Bs + row * 64 + ((quad ^ (row & 3)) << 4));
    }
#pragma unroll
    for (int mi = 0; mi < 4; mi++)
#pragma unroll
      for (int ni = 0; ni < 4; ni++)
        acc[mi][ni] = __builtin_amdgcn_mfma_f32_16x16x32_bf16(af[mi], bfr[ni], acc[mi][ni], 0, 0, 0);

    asm volatile("s_waitcnt lgkmcnt(0)" ::: "memory");   // frag reads complete
    __builtin_amdgcn_s_barrier();                        // buffer free for prefetch
    asm volatile("" ::: "memory");
  }

#pragma unroll
  for (int mi = 0; mi < 4; mi++)
#pragma unroll
    for (int ni = 0; ni < 4; ni++)
#pragma unroll
      for (int r = 0; r < 4; r++) {
        int row = bm0 + wm + mi * 16 + quad * 4 + r;   // m index (= b*2048+s)
        int col = bn0 + wn + ni * 16 + l16;            // n index
        float v = acc[mi][ni][r];
        if (MODE == 3) {
          ((float*)Cout)[(size_t)row * N + col] = v;
        } else if (MODE == 0) {
          int b = row >> 11, s = row & 2047;
          int h = col >> 7, d = col & 127;
          size_t idx = ((size_t)(b * NH + h) * S_DIM + s) * HD + d;
          ((__bf16*)Cout)[idx] = (__bf16)v;
        } else {  // MODE 4: merged K + Vt
          int b = row >> 11, s = row & 2047;
          size_t idx;
          if (col < 1024) {
            int h = col >> 7, d = col & 127;
            idx = ((size_t)(b * NKV + h) * S_DIM + s) * HD + d;              // K
          } else {
            int c = col - 1024;
            int h = c >> 7, d = c & 127;
            idx = 4194304 + ((size_t)(b * NKV + h) * HD + d) * S_DIM + s;    // Vt
          }
          ((__bf16*)Cout)[idx] = (__bf16)v;
        }
      }
}

// ---------------------------------------------------------------- RoPE (in place)
// x layout [B, nh, S, D]; pairs (j, j+64) rotated. lognh = log2(nh).
__global__ void rope_kernel(__bf16* __restrict__ x, const int* __restrict__ pos, int lognh) {
  int t = blockIdx.x * 256 + threadIdx.x;
  int j = t & 63;
  int s = (t >> 6) & (S_DIM - 1);
  int bh = t >> 17;
  int b = bh >> lognh;
  float p = (float)pos[b * S_DIM + s];
  float invf = exp2f((float)j * (-13.2877123795494f / 64.0f));
  float ang = p * invf;
  float sn, cs;
  sincosf(ang, &sn, &cs);
  size_t base = ((size_t)bh * S_DIM + s) * HD;
  float x1 = (float)x[base + j];
  float x2 = (float)x[base + j + 64];
  x[base + j]      = (__bf16)(x1 * cs - x2 * sn);
  x[base + j + 64] = (__bf16)(x2 * cs + x1 * sn);
}

// ---------------------------------------------------------------- flash attention
// Q [B,32,S,D], K [B,8,S,D], Vt [B,8,D,S] bf16 -> O [B,S,32*128] bf16.
// Block: 512 thr (8 waves), Q-tile 128 (16 q-rows/wave), K-tile 64, causal.
// Complementary Q-tile pairs (qt, 15-qt): every block does exactly 34 K-tiles,
// grid = 512 = 2 blocks/CU fully resident.
// SWAPPED QK^T (T12 core): sacc = mfma(K_frag, Q_frag) -> S^T tiles, so each
// lane owns P-values of ONE q-row (q = l16). Row max/sum become in-lane trees
// + 2 shfl_xor (was 4-deep chains x 4 rows); P writes pack to 4x ds_write_b64
// (was 16 scalar b16). m/l state: 2 scalars (was 8 floats).
// R4 lesson: keep per-thread state lean or the K-loop spills to scratch.
__device__ __forceinline__ void stage_kv(const __bf16* __restrict__ Kg,
                                         const __bf16* __restrict__ Vg,
                                         char* Kb, char* Vb, int k0, int tid) {
#pragma unroll
  for (int i = 0; i < 2; i++) {
    int slot = i * 512 + tid;                       // 64 rows x 16 units
    int row = slot >> 4;
    int u = (slot & 15) ^ (row & 15);               // inverse-swizzled source
    gload_lds16(Kg + (size_t)(k0 + row) * HD + u * 8, Kb + slot * 16);
  }
#pragma unroll
  for (int i = 0; i < 2; i++) {
    int slot = i * 512 + tid;                       // 128 rows x 8 units
    int row = slot >> 3;
    int u = (slot & 7) ^ (row & 7);
    gload_lds16(Vg + (size_t)row * S_DIM + k0 + u * 8, Vb + slot * 16);
  }
}

__global__ __launch_bounds__(512, 4)
void attn_kernel(const __bf16* __restrict__ Q, const __bf16* __restrict__ K,
                 const __bf16* __restrict__ Vt, __bf16* __restrict__ O) {
  __shared__ uint4 smem4[5120];            // 81920 B
  char* smem = (char*)smem4;
  char* Ps = smem + 65536;                 // 128 rows x 128 B
  const int tid = threadIdx.x;
  const int lane = tid & 63, wave = tid >> 6;
  const int quad = lane >> 4, l16 = lane & 15;
  const int h = blockIdx.y, b = blockIdx.z;
  const int kvh = h >> 2;
  const __bf16* Kg = K + (size_t)(b * NKV + kvh) * S_DIM * HD;
  const __bf16* Vg = Vt + (size_t)(b * NKV + kvh) * HD * S_DIM;
  const float scale = 0.08838834764831845f;   // 1/sqrt(128)

  for (int pass = 0; pass < 2; ++pass) {
    const int qt = pass ? (15 - (int)blockIdx.x) : (int)blockIdx.x;
    const int q0 = qt * 128;
    const __bf16* Qg = Q + ((size_t)(b * NH + h) * S_DIM + q0) * HD;
    const int nkt = qt * 2 + 2;
    const int qrow_lane = q0 + wave * 16 + l16;   // this lane's q-row (softmax)
    const int prow = wave * 16 + l16;             // P LDS row for this lane

    // Q fragments in registers (wave owns 16 q-rows); layout doubles as B-operand
    bf16x8 qf[4];
#pragma unroll
    for (int ks = 0; ks < 4; ks++)
      qf[ks] = *(const bf16x8*)(Qg + (wave * 16 + l16) * HD + (ks * 4 + quad) * 8);

    floatx4 oacc[8] = {};
    float mrow = -1e30f, lrow = 0.f;

    // prologue: stage tile 0 into buffer 0
    stage_kv(Kg, Vg, smem, smem + 32768, 0, tid);

    for (int kt = 0; kt < nkt; kt++) {
      char* Kc = smem + (kt & 1) * 16384;
      char* Vc = smem + 32768 + (kt & 1) * 16384;
      const int k0 = kt * 64;

      if (kt + 1 < nkt) {
        stage_kv(Kg, Vg, smem + ((kt + 1) & 1) * 16384,
                 smem + 32768 + ((kt + 1) & 1) * 16384, k0 + 64, tid);
        asm volatile("s_waitcnt vmcnt(4)" ::: "memory");
      } else {
        asm volatile("s_waitcnt vmcnt(0)" ::: "memory");
      }
      __builtin_amdgcn_s_barrier();            // tile kt data visible to all waves
      asm volatile("" ::: "memory");

      // ---- S^T = K Q^T  (swapped operands; fragments unchanged)
      // sacc[n][r] = S[key = k0 + n*16 + quad*4 + r][q = qrow_lane]
      floatx4 sacc[4] = {};
#pragma unroll
      for (int ks = 0; ks < 4; ks++) {
        bf16x8 bk[4];
#pragma unroll
        for (int n = 0; n < 4; n++) {
          int row = n * 16 + l16;
          bk[n] = *(const bf16x8*)(Kc + row * 256 + (((ks * 4 + quad) ^ (row & 15)) << 4));
        }
#pragma unroll
        for (int n = 0; n < 4; n++)
          sacc[n] = __builtin_amdgcn_mfma_f32_16x16x32_bf16(bk[n], qf[ks], sacc[n], 0, 0, 0);
      }

      // ---- online softmax: lane owns 16 P-values of q-row l16
      const bool maskt = (kt >= nkt - 2);      // diagonal-crossing tiles
      float pm[4][4];
#pragma unroll
      for (int n = 0; n < 4; n++)
#pragma unroll
        for (int r = 0; r < 4; r++) {
          float sv = sacc[n][r] * scale;
          if (maskt) {
            int kcol = k0 + n * 16 + quad * 4 + r;
            if (kcol > qrow_lane) sv = -1e30f;
          }
          pm[n][r] = sv;
        }
      // in-lane max tree (16 vals) + 2 shfls across quads (full 64-key row)
      float mx[4];
#pragma unroll
      for (int n = 0; n < 4; n++)
        mx[n] = fmaxf(fmaxf(pm[n][0], pm[n][1]), fmaxf(pm[n][2], pm[n][3]));
      float tmax = fmaxf(fmaxf(mx[0], mx[1]), fmaxf(mx[2], mx[3]));
      tmax = fmaxf(tmax, __shfl_xor(tmax, 16));
      tmax = fmaxf(tmax, __shfl_xor(tmax, 32));
      float nm = fmaxf(mrow, tmax);
      float al = __expf(mrow - nm);
      mrow = nm;
      float sx[4];
#pragma unroll
      for (int n = 0; n < 4; n++) {
#pragma unroll
        for (int r = 0; r < 4; r++) pm[n][r] = __expf(pm[n][r] - nm);
        sx[n] = (pm[n][0] + pm[n][1]) + (pm[n][2] + pm[n][3]);
      }
      float rs = (sx[0] + sx[1]) + (sx[2] + sx[3]);
      rs += __shfl_xor(rs, 16);
      rs += __shfl_xor(rs, 32);
      lrow = lrow * al + rs;
      // broadcast al to oacc-row owners (oacc row q = quad*4+r lives at lane q)
#pragma unroll
      for (int r = 0; r < 4; r++) {
        float alr = __shfl(al, quad * 4 + r);
#pragma unroll
        for (int n = 0; n < 8; n++) oacc[n][r] *= alr;
      }
      // write P (bf16) to LDS — 4x ds_write_b64, wave-private rows
#pragma unroll
      for (int n = 0; n < 4; n++) {
        bf16x4 w;
        w.x = (__bf16)pm[n][0]; w.y = (__bf16)pm[n][1];
        w.z = (__bf16)pm[n][2]; w.w = (__bf16)pm[n][3];
        int unit = n * 2 + (quad >> 1);                 // (k = n*16+quad*4)/8
        *(bf16x4*)(Ps + prow * 128 + ((unit ^ (prow & 7)) << 4) + (quad & 1) * 8) = w;
      }
      asm volatile("s_waitcnt lgkmcnt(0)" ::: "memory");   // P writes landed

      // ---- O += P V
#pragma unroll
      for (int ks = 0; ks < 2; ks++) {
        bf16x8 ap = *(const bf16x8*)(Ps + prow * 128 + (((ks * 4 + quad) ^ (prow & 7)) << 4));
#pragma unroll
        for (int n = 0; n < 8; n++) {
          int vrow = n * 16 + l16;
          bf16x8 bv = *(const bf16x8*)(Vc + vrow * 128 + (((ks * 4 + quad) ^ (vrow & 7)) << 4));
          oacc[n] = __builtin_amdgcn_mfma_f32_16x16x32_bf16(ap, bv, oacc[n], 0, 0, 0);
        }
      }

      asm volatile("" ::: "memory");
      __builtin_amdgcn_s_barrier();            // buffers free for next prefetch
      asm volatile("" ::: "memory");
    }

    // epilogue: O /= l, store to [B,S,H*D]
    float lr[4];
#pragma unroll
    for (int r = 0; r < 4; r++) lr[r] = __shfl(lrow, quad * 4 + r);
#pragma unroll
    for (int n = 0; n < 8; n++)
#pragma unroll
      for (int r = 0; r < 4; r++) {
        int row = wave * 16 + quad * 4 + r;
        int col = n * 16 + l16;
        float v = oacc[n][r] / lr[r];
        O[(size_t)(b * S_DIM + q0 + row) * HID + h * HD + col] = (__bf16)v;
      }
  }
}

// ---------------------------------------------------------------- launch
extern "C" void kernel_launch(void* const* d_in, const int* in_sizes, int n_in,
                              void* d_out, int out_size, void* d_ws, size_t ws_size,
                              hipStream_t stream) {
  const float* hs = (const float*)d_in[0];
  const float* wq = (const float*)d_in[1];
  const float* wk = (const float*)d_in[2];
  const float* wv = (const float*)d_in[3];
  const float* wo = (const float*)d_in[4];
  // d_in[5] = attention_mask (pure causal; implemented directly)
  const int* pos = (const int*)d_in[6];

  char* ws = (char*)d_ws;
  __bf16* Xb  = (__bf16*)(ws);                 // 33.55 MB  [4096][4096]
  __bf16* Wqb = (__bf16*)(ws + 33554432);      // 33.55 MB
  __bf16* Wkb = (__bf16*)(ws + 67108864);      //  8.39 MB (contig with Wvb)
  __bf16* Wvb = (__bf16*)(ws + 75497472);      //  8.39 MB
  __bf16* Wob = (__bf16*)(ws + 83886080);      // 33.55 MB
  __bf16* Qb  = (__bf16*)(ws + 117440512);     // 33.55 MB  [B,32,S,D]
  __bf16* Kb  = (__bf16*)(ws + 150994944);     //  8.39 MB  [B,8,S,D] (contig with Vtb)
  __bf16* Vtb = (__bf16*)(ws + 159383552);     //  8.39 MB  [B,8,D,S]
  __bf16* Ab  = (__bf16*)(ws + 167772160);     // 33.55 MB  attn out [4096][4096]
  if (ws_size < 201326592u) return;

  const int M = B_DIM * S_DIM;  // 4096

  f2bf_kernel<<<16384, 256, 0, stream>>>(hs, Xb, 16777216);
  f2bf_kernel<<<16384, 256, 0, stream>>>(wq, Wqb, 16777216);
  f2bf_kernel<<<4096, 256, 0, stream>>>(wk, Wkb, 4194304);
  f2bf_kernel<<<4096, 256, 0, stream>>>(wv, Wvb, 4194304);
  f2bf_kernel<<<16384, 256, 0, stream>>>(wo, Wob, 16777216);

  gemm_bt<0><<<dim3(32, 32), 256, 0, stream>>>(Xb, Wqb, Qb, M, 4096, 4096);
  // merged K+V projection: Wkb|Wvb contiguous [2048][4096], Kb|Vtb contiguous out
  gemm_bt<4><<<dim3(16, 32), 256, 0, stream>>>(Xb, Wkb, Kb, M, 2048, 4096);

  rope_kernel<<<32768, 256, 0, stream>>>(Qb, pos, 5);   // B*32*2048*64 / 256
  rope_kernel<<<8192, 256, 0, stream>>>(Kb, pos, 3);    // B*8*2048*64 / 256

  attn_kernel<<<dim3(8, 32, 2), 512, 0, stream>>>(Qb, Kb, Vtb, Ab);

  gemm_bt<3><<<dim3(32, 32), 256, 0, stream>>>(Ab, Wob, d_out, M, 4096, 4096);
}

// Round 8
// 788.683 us; speedup vs baseline: 1.4646x; 1.0031x over previous
//
#include <hip/hip_runtime.h>

typedef __attribute__((ext_vector_type(8))) __bf16 bf16x8;
typedef __attribute__((ext_vector_type(4))) __bf16 bf16x4;
typedef __attribute__((ext_vector_type(4))) float floatx4;

#define B_DIM 2
#define S_DIM 2048
#define NH    32
#define NKV   8
#define HD    128
#define HID   4096

// ---------------------------------------------------------------- helpers
__device__ __forceinline__ void gload_lds16(const void* gsrc, void* ldst) {
  __builtin_amdgcn_global_load_lds(
      (__attribute__((address_space(1))) unsigned int*)(void*)gsrc,
      (__attribute__((address_space(3))) unsigned int*)ldst, 16, 0, 0);
}

// ---------------------------------------------------------------- fp32 -> bf16
__global__ void f2bf_kernel(const float* __restrict__ in, __bf16* __restrict__ out, int n) {
  int i = (blockIdx.x * 256 + threadIdx.x) * 4;
  if (i >= n) return;
  float4 v = *(const float4*)(in + i);
  bf16x4 o;
  o.x = (__bf16)v.x; o.y = (__bf16)v.y; o.z = (__bf16)v.z; o.w = (__bf16)v.w;
  *(bf16x4*)(out + i) = o;
}

// ---------------------------------------------------------------- GEMM C = A * B^T
// A [M][K] bf16 row-major, Bw [N][K] bf16 row-major.
// 128x128 tile, BK=32. TRIPLE-buffered LDS, prefetch depth 2, ONE barrier per
// K-step: with 3 buffers, the stage target at iter kt is the buffer read at
// kt-1, and the kt barrier proves all waves finished kt-1 -> no second barrier.
// LDS unit swizzle u ^= (row>>1)&3 (bank-relevant bits: (row&1)*64 + u*16 mod
// 128 -> rows 0..7 hit all 8 16B slots, conflict-free), applied on BOTH the
// pre-swizzled global source (global_load_lds writes linearly) and the reads.
// MODE 0: store bf16 permuted to Q layout [B,32,S,D]
// MODE 3: store fp32 plain row-major [M][N]
// MODE 4: merged K+V projection: col<1024 -> K layout [B,8,S,D];
//         col>=1024 -> Vt layout [B,8,D,S] at +4194304 bf16 elements.
__device__ __forceinline__ void gemm_stage(const __bf16* __restrict__ Ag,
                                           const __bf16* __restrict__ Bg,
                                           char* buf, int K, int k0, int tid) {
  char* As = buf;
  char* Bs = buf + 8192;
#pragma unroll
  for (int i = 0; i < 2; i++) {
    int slot = i * 256 + tid;                  // 128 rows x 4 units (16 B)
    int row = slot >> 2;
    int u = (slot & 3) ^ ((row >> 1) & 3);     // inverse-swizzled source unit
    gload_lds16(Ag + (size_t)row * K + k0 + u * 8, As + slot * 16);
  }
#pragma unroll
  for (int i = 0; i < 2; i++) {
    int slot = i * 256 + tid;
    int row = slot >> 2;
    int u = (slot & 3) ^ ((row >> 1) & 3);
    gload_lds16(Bg + (size_t)row * K + k0 + u * 8, Bs + slot * 16);
  }
}

template <int MODE>
__global__ __launch_bounds__(256)
void gemm_bt(const __bf16* __restrict__ A, const __bf16* __restrict__ Bw,
             void* __restrict__ Cout, int M, int N, int K) {
  __shared__ uint4 smem4[3072];            // 48 KB: 3 x (As 8K + Bs 8K)
  char* smem = (char*)smem4;
  const int tid = threadIdx.x;
  const int lane = tid & 63, wave = tid >> 6;
  const int quad = lane >> 4, l16 = lane & 15;
  const int bm0 = blockIdx.y * 128, bn0 = blockIdx.x * 128;
  const __bf16* Ag = A + (size_t)bm0 * K;
  const __bf16* Bg = Bw + (size_t)bn0 * K;
  const int wm = (wave >> 1) * 64, wn = (wave & 1) * 64;

  floatx4 acc[4][4] = {};

  char* pA = smem;                 // buffer read this iteration
  char* pB = smem + 16384;         // next
  char* pC = smem + 32768;         // stage target (= buffer read last iter)

  const int nkt = K >> 5;
  // prologue: stage tiles 0 and 1
  gemm_stage(Ag, Bg, pA, K, 0, tid);
  if (nkt > 1) gemm_stage(Ag, Bg, pB, K, 32, tid);

  for (int kt = 0; kt < nkt; kt++) {
    if (kt + 1 < nkt) {
      asm volatile("s_waitcnt vmcnt(4)" ::: "memory");   // tile kt landed
    } else {
      asm volatile("s_waitcnt vmcnt(0)" ::: "memory");
    }
    __builtin_amdgcn_s_barrier();    // all waves here => done reading pC's data
    asm volatile("" ::: "memory");

    if (kt + 2 < nkt) gemm_stage(Ag, Bg, pC, K, (kt + 2) << 5, tid);

    char* As = pA;
    char* Bs = pA + 8192;
    bf16x8 af[4], bfr[4];
#pragma unroll
    for (int i = 0; i < 4; i++) {
      int row = wm + i * 16 + l16;
      af[i] = *(const bf16x8*)(As + row * 64 + ((quad ^ ((row >> 1) & 3)) << 4));
    }
#pragma unroll
    for (int i = 0; i < 4; i++) {
      int row = wn + i * 16 + l16;
      bfr[i] = *(const bf16x8*)(Bs + row * 64 + ((quad ^ ((row >> 1) & 3)) << 4));
    }
#pragma unroll
    for (int mi = 0; mi < 4; mi++)
#pragma unroll
      for (int ni = 0; ni < 4; ni++)
        acc[mi][ni] = __builtin_amdgcn_mfma_f32_16x16x32_bf16(af[mi], bfr[ni], acc[mi][ni], 0, 0, 0);

    asm volatile("s_waitcnt lgkmcnt(0)" ::: "memory");   // reads drained
    // rotate buffers (named pointers, no runtime indexing)
    char* t = pA; pA = pB; pB = pC; pC = t;
  }

#pragma unroll
  for (int mi = 0; mi < 4; mi++)
#pragma unroll
    for (int ni = 0; ni < 4; ni++)
#pragma unroll
      for (int r = 0; r < 4; r++) {
        int row = bm0 + wm + mi * 16 + quad * 4 + r;   // m index (= b*2048+s)
        int col = bn0 + wn + ni * 16 + l16;            // n index
        float v = acc[mi][ni][r];
        if (MODE == 3) {
          ((float*)Cout)[(size_t)row * N + col] = v;
        } else if (MODE == 0) {
          int b = row >> 11, s = row & 2047;
          int h = col >> 7, d = col & 127;
          size_t idx = ((size_t)(b * NH + h) * S_DIM + s) * HD + d;
          ((__bf16*)Cout)[idx] = (__bf16)v;
        } else {  // MODE 4: merged K + Vt
          int b = row >> 11, s = row & 2047;
          size_t idx;
          if (col < 1024) {
            int h = col >> 7, d = col & 127;
            idx = ((size_t)(b * NKV + h) * S_DIM + s) * HD + d;              // K
          } else {
            int c = col - 1024;
            int h = c >> 7, d = c & 127;
            idx = 4194304 + ((size_t)(b * NKV + h) * HD + d) * S_DIM + s;    // Vt
          }
          ((__bf16*)Cout)[idx] = (__bf16)v;
        }
      }
}

// ---------------------------------------------------------------- RoPE (in place)
// x layout [B, nh, S, D]; pairs (j, j+64) rotated. lognh = log2(nh).
__global__ void rope_kernel(__bf16* __restrict__ x, const int* __restrict__ pos, int lognh) {
  int t = blockIdx.x * 256 + threadIdx.x;
  int j = t & 63;
  int s = (t >> 6) & (S_DIM - 1);
  int bh = t >> 17;
  int b = bh >> lognh;
  float p = (float)pos[b * S_DIM + s];
  float invf = exp2f((float)j * (-13.2877123795494f / 64.0f));
  float ang = p * invf;
  float sn, cs;
  sincosf(ang, &sn, &cs);
  size_t base = ((size_t)bh * S_DIM + s) * HD;
  float x1 = (float)x[base + j];
  float x2 = (float)x[base + j + 64];
  x[base + j]      = (__bf16)(x1 * cs - x2 * sn);
  x[base + j + 64] = (__bf16)(x2 * cs + x1 * sn);
}

// ---------------------------------------------------------------- flash attention
// (byte-identical to the verified R7 kernel — 791 us run)
// Q [B,32,S,D], K [B,8,S,D], Vt [B,8,D,S] bf16 -> O [B,S,32*128] bf16.
// Block: 512 thr (8 waves), Q-tile 128 (16 q-rows/wave), K-tile 64, causal.
// Complementary Q-tile pairs (qt, 15-qt): every block does exactly 34 K-tiles,
// grid = 512 = 2 blocks/CU fully resident.
// SWAPPED QK^T: sacc = mfma(K_frag, Q_frag) -> lane owns P-row; in-lane trees
// + 2 shfl_xor; P writes 4x ds_write_b64. R4 lesson: keep state lean.
__device__ __forceinline__ void stage_kv(const __bf16* __restrict__ Kg,
                                         const __bf16* __restrict__ Vg,
                                         char* Kb, char* Vb, int k0, int tid) {
#pragma unroll
  for (int i = 0; i < 2; i++) {
    int slot = i * 512 + tid;                       // 64 rows x 16 units
    int row = slot >> 4;
    int u = (slot & 15) ^ (row & 15);               // inverse-swizzled source
    gload_lds16(Kg + (size_t)(k0 + row) * HD + u * 8, Kb + slot * 16);
  }
#pragma unroll
  for (int i = 0; i < 2; i++) {
    int slot = i * 512 + tid;                       // 128 rows x 8 units
    int row = slot >> 3;
    int u = (slot & 7) ^ (row & 7);
    gload_lds16(Vg + (size_t)row * S_DIM + k0 + u * 8, Vb + slot * 16);
  }
}

__global__ __launch_bounds__(512, 4)
void attn_kernel(const __bf16* __restrict__ Q, const __bf16* __restrict__ K,
                 const __bf16* __restrict__ Vt, __bf16* __restrict__ O) {
  __shared__ uint4 smem4[5120];            // 81920 B
  char* smem = (char*)smem4;
  char* Ps = smem + 65536;                 // 128 rows x 128 B
  const int tid = threadIdx.x;
  const int lane = tid & 63, wave = tid >> 6;
  const int quad = lane >> 4, l16 = lane & 15;
  const int h = blockIdx.y, b = blockIdx.z;
  const int kvh = h >> 2;
  const __bf16* Kg = K + (size_t)(b * NKV + kvh) * S_DIM * HD;
  const __bf16* Vg = Vt + (size_t)(b * NKV + kvh) * HD * S_DIM;
  const float scale = 0.08838834764831845f;   // 1/sqrt(128)

  for (int pass = 0; pass < 2; ++pass) {
    const int qt = pass ? (15 - (int)blockIdx.x) : (int)blockIdx.x;
    const int q0 = qt * 128;
    const __bf16* Qg = Q + ((size_t)(b * NH + h) * S_DIM + q0) * HD;
    const int nkt = qt * 2 + 2;
    const int qrow_lane = q0 + wave * 16 + l16;   // this lane's q-row (softmax)
    const int prow = wave * 16 + l16;             // P LDS row for this lane

    // Q fragments in registers (wave owns 16 q-rows); layout doubles as B-operand
    bf16x8 qf[4];
#pragma unroll
    for (int ks = 0; ks < 4; ks++)
      qf[ks] = *(const bf16x8*)(Qg + (wave * 16 + l16) * HD + (ks * 4 + quad) * 8);

    floatx4 oacc[8] = {};
    float mrow = -1e30f, lrow = 0.f;

    // prologue: stage tile 0 into buffer 0
    stage_kv(Kg, Vg, smem, smem + 32768, 0, tid);

    for (int kt = 0; kt < nkt; kt++) {
      char* Kc = smem + (kt & 1) * 16384;
      char* Vc = smem + 32768 + (kt & 1) * 16384;
      const int k0 = kt * 64;

      if (kt + 1 < nkt) {
        stage_kv(Kg, Vg, smem + ((kt + 1) & 1) * 16384,
                 smem + 32768 + ((kt + 1) & 1) * 16384, k0 + 64, tid);
        asm volatile("s_waitcnt vmcnt(4)" ::: "memory");
      } else {
        asm volatile("s_waitcnt vmcnt(0)" ::: "memory");
      }
      __builtin_amdgcn_s_barrier();            // tile kt data visible to all waves
      asm volatile("" ::: "memory");

      // ---- S^T = K Q^T  (swapped operands; fragments unchanged)
      // sacc[n][r] = S[key = k0 + n*16 + quad*4 + r][q = qrow_lane]
      floatx4 sacc[4] = {};
#pragma unroll
      for (int ks = 0; ks < 4; ks++) {
        bf16x8 bk[4];
#pragma unroll
        for (int n = 0; n < 4; n++) {
          int row = n * 16 + l16;
          bk[n] = *(const bf16x8*)(Kc + row * 256 + (((ks * 4 + quad) ^ (row & 15)) << 4));
        }
#pragma unroll
        for (int n = 0; n < 4; n++)
          sacc[n] = __builtin_amdgcn_mfma_f32_16x16x32_bf16(bk[n], qf[ks], sacc[n], 0, 0, 0);
      }

      // ---- online softmax: lane owns 16 P-values of q-row l16
      const bool maskt = (kt >= nkt - 2);      // diagonal-crossing tiles
      float pm[4][4];
#pragma unroll
      for (int n = 0; n < 4; n++)
#pragma unroll
        for (int r = 0; r < 4; r++) {
          float sv = sacc[n][r] * scale;
          if (maskt) {
            int kcol = k0 + n * 16 + quad * 4 + r;
            if (kcol > qrow_lane) sv = -1e30f;
          }
          pm[n][r] = sv;
        }
      // in-lane max tree (16 vals) + 2 shfls across quads (full 64-key row)
      float mx[4];
#pragma unroll
      for (int n = 0; n < 4; n++)
        mx[n] = fmaxf(fmaxf(pm[n][0], pm[n][1]), fmaxf(pm[n][2], pm[n][3]));
      float tmax = fmaxf(fmaxf(mx[0], mx[1]), fmaxf(mx[2], mx[3]));
      tmax = fmaxf(tmax, __shfl_xor(tmax, 16));
      tmax = fmaxf(tmax, __shfl_xor(tmax, 32));
      float nm = fmaxf(mrow, tmax);
      float al = __expf(mrow - nm);
      mrow = nm;
      float sx[4];
#pragma unroll
      for (int n = 0; n < 4; n++) {
#pragma unroll
        for (int r = 0; r < 4; r++) pm[n][r] = __expf(pm[n][r] - nm);
        sx[n] = (pm[n][0] + pm[n][1]) + (pm[n][2] + pm[n][3]);
      }
      float rs = (sx[0] + sx[1]) + (sx[2] + sx[3]);
      rs += __shfl_xor(rs, 16);
      rs += __shfl_xor(rs, 32);
      lrow = lrow * al + rs;
      // broadcast al to oacc-row owners (oacc row q = quad*4+r lives at lane q)
#pragma unroll
      for (int r = 0; r < 4; r++) {
        float alr = __shfl(al, quad * 4 + r);
#pragma unroll
        for (int n = 0; n < 8; n++) oacc[n][r] *= alr;
      }
      // write P (bf16) to LDS — 4x ds_write_b64, wave-private rows
#pragma unroll
      for (int n = 0; n < 4; n++) {
        bf16x4 w;
        w.x = (__bf16)pm[n][0]; w.y = (__bf16)pm[n][1];
        w.z = (__bf16)pm[n][2]; w.w = (__bf16)pm[n][3];
        int unit = n * 2 + (quad >> 1);                 // (k = n*16+quad*4)/8
        *(bf16x4*)(Ps + prow * 128 + ((unit ^ (prow & 7)) << 4) + (quad & 1) * 8) = w;
      }
      asm volatile("s_waitcnt lgkmcnt(0)" ::: "memory");   // P writes landed

      // ---- O += P V
#pragma unroll
      for (int ks = 0; ks < 2; ks++) {
        bf16x8 ap = *(const bf16x8*)(Ps + prow * 128 + (((ks * 4 + quad) ^ (prow & 7)) << 4));
#pragma unroll
        for (int n = 0; n < 8; n++) {
          int vrow = n * 16 + l16;
          bf16x8 bv = *(const bf16x8*)(Vc + vrow * 128 + (((ks * 4 + quad) ^ (vrow & 7)) << 4));
          oacc[n] = __builtin_amdgcn_mfma_f32_16x16x32_bf16(ap, bv, oacc[n], 0, 0, 0);
        }
      }

      asm volatile("" ::: "memory");
      __builtin_amdgcn_s_barrier();            // buffers free for next prefetch
      asm volatile("" ::: "memory");
    }

    // epilogue: O /= l, store to [B,S,H*D]
    float lr[4];
#pragma unroll
    for (int r = 0; r < 4; r++) lr[r] = __shfl(lrow, quad * 4 + r);
#pragma unroll
    for (int n = 0; n < 8; n++)
#pragma unroll
      for (int r = 0; r < 4; r++) {
        int row = wave * 16 + quad * 4 + r;
        int col = n * 16 + l16;
        float v = oacc[n][r] / lr[r];
        O[(size_t)(b * S_DIM + q0 + row) * HID + h * HD + col] = (__bf16)v;
      }
  }
}

// ---------------------------------------------------------------- launch
extern "C" void kernel_launch(void* const* d_in, const int* in_sizes, int n_in,
                              void* d_out, int out_size, void* d_ws, size_t ws_size,
                              hipStream_t stream) {
  const float* hs = (const float*)d_in[0];
  const float* wq = (const float*)d_in[1];
  const float* wk = (const float*)d_in[2];
  const float* wv = (const float*)d_in[3];
  const float* wo = (const float*)d_in[4];
  // d_in[5] = attention_mask (pure causal; implemented directly)
  const int* pos = (const int*)d_in[6];

  char* ws = (char*)d_ws;
  __bf16* Xb  = (__bf16*)(ws);                 // 33.55 MB  [4096][4096]
  __bf16* Wqb = (__bf16*)(ws + 33554432);      // 33.55 MB
  __bf16* Wkb = (__bf16*)(ws + 67108864);      //  8.39 MB (contig with Wvb)
  __bf16* Wvb = (__bf16*)(ws + 75497472);      //  8.39 MB
  __bf16* Wob = (__bf16*)(ws + 83886080);      // 33.55 MB
  __bf16* Qb  = (__bf16*)(ws + 117440512);     // 33.55 MB  [B,32,S,D]
  __bf16* Kb  = (__bf16*)(ws + 150994944);     //  8.39 MB  [B,8,S,D] (contig with Vtb)
  __bf16* Vtb = (__bf16*)(ws + 159383552);     //  8.39 MB  [B,8,D,S]
  __bf16* Ab  = (__bf16*)(ws + 167772160);     // 33.55 MB  attn out [4096][4096]
  if (ws_size < 201326592u) return;

  const int M = B_DIM * S_DIM;  // 4096

  f2bf_kernel<<<16384, 256, 0, stream>>>(hs, Xb, 16777216);
  f2bf_kernel<<<16384, 256, 0, stream>>>(wq, Wqb, 16777216);
  f2bf_kernel<<<4096, 256, 0, stream>>>(wk, Wkb, 4194304);
  f2bf_kernel<<<4096, 256, 0, stream>>>(wv, Wvb, 4194304);
  f2bf_kernel<<<16384, 256, 0, stream>>>(wo, Wob, 16777216);

  gemm_bt<0><<<dim3(32, 32), 256, 0, stream>>>(Xb, Wqb, Qb, M, 4096, 4096);
  // merged K+V projection: Wkb|Wvb contiguous [2048][4096], Kb|Vtb contiguous out
  gemm_bt<4><<<dim3(16, 32), 256, 0, stream>>>(Xb, Wkb, Kb, M, 2048, 4096);

  rope_kernel<<<32768, 256, 0, stream>>>(Qb, pos, 5);   // B*32*2048*64 / 256
  rope_kernel<<<8192, 256, 0, stream>>>(Kb, pos, 3);    // B*8*2048*64 / 256

  attn_kernel<<<dim3(8, 32, 2), 512, 0, stream>>>(Qb, Kb, Vtb, Ab);

  gemm_bt<3><<<dim3(32, 32), 256, 0, stream>>>(Ab, Wob, d_out, M, 4096, 4096);
}